// Round 7
// baseline (21.024 us; speedup 1.0000x reference)
//
#include <hip/hip_runtime.h>

#define NELEM 8192
#define JTILE 32
#define NJT   (NELEM / JTILE)     // 256 j-tiles
#define IPT   16                  // i's per thread (contiguous run)
#define IBLK  (256 * IPT)         // 4096 i's per block
#define NIB   (NELEM / IBLK)      // 2 i-blocks
#define NBLK  (NIB * NJT)         // 512 blocks (power of 2)
#define SCB   NBLK                // scalar-sum base (float index in ws)
#define GRPSZ 64                  // blocks per ticket group (power of 2)
#define NGRP  (NBLK / GRPSZ)      // 8 groups
#define CNTB  1024                // group counters: float idx 1024 + g*64 (256B apart)
#define FINC  (CNTB + NGRP * 64)  // final counter float idx (1536)

// Loss = [sum_{i<j} fi fj max((pi-pj)(ti-tj)/100, 0)] / C(M,2),  M = #flagged.
// With t' = 0.01*t and max(x,0) = (x+|x|)/2 over the full ordered square:
//   A = sum_{i,j} fi fj (pi-pj)(t'i-t'j) = 2[M*T - P*Q]   (closed form)
//       T = sum f p t', P = sum f p, Q = sum f t'
//   B = sum_{i,j} fi fj |pi-pj||t'i-t'j|                  (pair loop)
//   Loss = (A + B) / (2 M (M-1))
// Unflagged j staged as (0,0):  B = B_raw - (N - M)*D,  D = sum f |p t'|.
// Inner op: 3 VALU/pair (sub, sub, fma; abs folds into VOP3 modifiers).
//
// Single kernel node, NO memset: HIERARCHICAL modular ticket.
//   level 1: 8 group counters on separate cache lines, 64 blocks each
//            (tail = 8 parallel 64-deep RMW chains, not 512 serialized)
//   level 2: final counter fed by the 8 group winners.
// Counters are NEVER reset: each call adds exactly 64 (resp. 8) increments,
// and since 64 | 2^32 and 8 | 2^32, any contiguous run from ANY start value
// (incl. 0xAA poison) contains exactly one ticket (old & (sz-1)) == sz-1.
// Release-sequence chains through both RMW levels: every partial write
// happens-before the final winner's reduction. Fixed reduction tree over
// fully-deterministic ws -> bit-identical output regardless of winner.
__global__ __launch_bounds__(256) void cindex_fused(
    const float* __restrict__ pred,
    const float* __restrict__ gt,
    const int* __restrict__ colT,
    const int* __restrict__ colF,
    float* __restrict__ ws,
    float* __restrict__ out)
{
    __shared__ float2 sj[JTILE];
    __shared__ float  wsum[4];
    __shared__ float  s5[4][5];
    __shared__ int    lastBlock;

    const int tid = threadIdx.x;
    const int ib  = blockIdx.x;   // 0..NIB-1
    const int tj  = blockIdx.y;   // 0..NJT-1
    const int bid = tj * NIB + ib;
    const int ct  = colT[0];      // 0
    const int cf  = colF[0];      // 1

    if (tid < JTILE) {
        const int j = tj * JTILE + tid;
        const float2 g = ((const float2*)gt)[j];
        const float tv = (ct == 0) ? g.x : g.y;
        const float fv = (cf == 0) ? g.x : g.y;
        const float pj = pred[j];
        const bool  fl = (fv == 1.0f);
        sj[tid] = make_float2(fl ? pj : 0.0f, fl ? tv * 0.01f : 0.0f);
    }
    __syncthreads();

    float p[IPT], t[IPT], f[IPT], acc[IPT];
    {
        const int i0 = ib * IBLK + tid * IPT;           // 64B-aligned
        const float4* p4 = (const float4*)(pred + i0);
        const float4* g4 = (const float4*)(gt + 2 * i0);
        float4 pr[IPT / 4], gr[IPT / 2];
        #pragma unroll
        for (int q = 0; q < IPT / 4; ++q) pr[q] = p4[q];
        #pragma unroll
        for (int q = 0; q < IPT / 2; ++q) gr[q] = g4[q];
        #pragma unroll
        for (int k = 0; k < IPT; ++k) {                 // static indices only
            p[k] = ((const float*)pr)[k];
            const float gx = ((const float*)gr)[2 * k];
            const float gy = ((const float*)gr)[2 * k + 1];
            const float tv = (ct == 0) ? gx : gy;
            const float fv = (cf == 0) ? gx : gy;
            t[k] = tv * 0.01f;
            f[k] = (fv == 1.0f) ? 1.0f : 0.0f;
            acc[k] = 0.0f;
        }
    }

    #pragma unroll 4
    for (int jj = 0; jj < JTILE; ++jj) {
        const float2 v = sj[jj];              // ds_read_b64 broadcast (uniform)
        #pragma unroll
        for (int k = 0; k < IPT; ++k)
            acc[k] = fmaf(fabsf(p[k] - v.x), fabsf(t[k] - v.y), acc[k]);
    }

    float s = 0.0f;
    #pragma unroll
    for (int k = 0; k < IPT; ++k) s = fmaf(f[k], acc[k], s);
    for (int off = 32; off > 0; off >>= 1) s += __shfl_down(s, off, 64);
    if ((tid & 63) == 0) wsum[tid >> 6] = s;

    // O(N) scalar sums, piggybacked on tj==0 blocks (i-data already live).
    if (tj == 0) {   // block-uniform
        float c = 0, sp = 0, st = 0, spt = 0, sab = 0;
        #pragma unroll
        for (int k = 0; k < IPT; ++k) {
            const float pt = p[k] * t[k];
            c   += f[k];
            sp   = fmaf(f[k], p[k], sp);
            st   = fmaf(f[k], t[k], st);
            spt  = fmaf(f[k], pt, spt);
            sab  = fmaf(f[k], fabsf(pt), sab);
        }
        for (int off = 32; off > 0; off >>= 1) {
            c   += __shfl_down(c,   off, 64);
            sp  += __shfl_down(sp,  off, 64);
            st  += __shfl_down(st,  off, 64);
            spt += __shfl_down(spt, off, 64);
            sab += __shfl_down(sab, off, 64);
        }
        if ((tid & 63) == 0) {
            const int w = tid >> 6;
            s5[w][0] = c;  s5[w][1] = sp;  s5[w][2] = st;
            s5[w][3] = spt; s5[w][4] = sab;
        }
    }
    __syncthreads();

    if (tid == 0) {
        const float bsum = wsum[0] + wsum[1] + wsum[2] + wsum[3];
        __hip_atomic_store(&ws[bid], bsum,
                           __ATOMIC_RELAXED, __HIP_MEMORY_SCOPE_AGENT);
        if (tj == 0) {
            #pragma unroll
            for (int m = 0; m < 5; ++m)
                __hip_atomic_store(&ws[SCB + ib * 5 + m],
                                   s5[0][m] + s5[1][m] + s5[2][m] + s5[3][m],
                                   __ATOMIC_RELAXED, __HIP_MEMORY_SCOPE_AGENT);
        }
        // Level 1: group ticket (64 blocks, own cache line).
        unsigned int* grpCnt = (unsigned int*)&ws[CNTB + (bid / GRPSZ) * 64];
        const unsigned old = __hip_atomic_fetch_add(grpCnt, 1u,
                                __ATOMIC_ACQ_REL, __HIP_MEMORY_SCOPE_AGENT);
        int isFinal = 0;
        if ((old & (GRPSZ - 1)) == GRPSZ - 1) {
            // Level 2: final ticket (8 group winners).
            unsigned int* finCnt = (unsigned int*)&ws[FINC];
            const unsigned o2 = __hip_atomic_fetch_add(finCnt, 1u,
                                    __ATOMIC_ACQ_REL, __HIP_MEMORY_SCOPE_AGENT);
            isFinal = ((o2 & (NGRP - 1)) == NGRP - 1) ? 1 : 0;
        }
        lastBlock = isFinal;
    }
    __syncthreads();
    if (!lastBlock) return;

    // Final-ticket block: reduce all partials (fixed tree -> deterministic).
    double d = 0.0;
    for (int i = tid; i < NBLK; i += 256)
        d += (double)__hip_atomic_load(&ws[i],
                        __ATOMIC_RELAXED, __HIP_MEMORY_SCOPE_AGENT);
    for (int off = 32; off > 0; off >>= 1) d += __shfl_down(d, off, 64);
    __shared__ double sd[4];
    if ((tid & 63) == 0) sd[tid >> 6] = d;
    __syncthreads();
    if (tid == 0) {
        const double Braw = sd[0] + sd[1] + sd[2] + sd[3];
        double M = 0, P = 0, Q = 0, T = 0, D = 0;
        for (int ibb = 0; ibb < NIB; ++ibb) {
            const float* o = ws + SCB + ibb * 5;
            M += (double)__hip_atomic_load(&o[0], __ATOMIC_RELAXED, __HIP_MEMORY_SCOPE_AGENT);
            P += (double)__hip_atomic_load(&o[1], __ATOMIC_RELAXED, __HIP_MEMORY_SCOPE_AGENT);
            Q += (double)__hip_atomic_load(&o[2], __ATOMIC_RELAXED, __HIP_MEMORY_SCOPE_AGENT);
            T += (double)__hip_atomic_load(&o[3], __ATOMIC_RELAXED, __HIP_MEMORY_SCOPE_AGENT);
            D += (double)__hip_atomic_load(&o[4], __ATOMIC_RELAXED, __HIP_MEMORY_SCOPE_AGENT);
        }
        const double A = 2.0 * (M * T - P * Q);
        const double B = Braw - ((double)NELEM - M) * D;
        out[0] = (float)((A + B) / (2.0 * M * (M - 1.0)));
    }
}

extern "C" void kernel_launch(void* const* d_in, const int* in_sizes, int n_in,
                              void* d_out, int out_size, void* d_ws, size_t ws_size,
                              hipStream_t stream) {
    const float* pred = (const float*)d_in[0];
    const float* gt   = (const float*)d_in[1];
    const int*   colT = (const int*)d_in[2];
    const int*   colF = (const int*)d_in[3];

    float* ws = (float*)d_ws;   // partials [0,512), scalars [512,522), counters [1024,1537)

    dim3 grid(NIB, NJT);
    cindex_fused<<<grid, 256, 0, stream>>>(pred, gt, colT, colF, ws, (float*)d_out);
}

// Round 8
// 16.618 us; speedup vs baseline: 1.2651x; 1.2651x over previous
//
#include <hip/hip_runtime.h>

#define NELEM 8192
#define JTILE 32
#define NJT   (NELEM / JTILE)     // 256 j-tiles
#define IPT   16                  // i's per thread (contiguous run)
#define IBLK  (256 * IPT)         // 4096 i's per block
#define NIB   (NELEM / IBLK)      // 2 i-blocks
#define NBLK  (NIB * NJT)         // 512 partial sums
#define SCB   NBLK                // scalar-sum base (float index in ws)

// Loss = [sum_{i<j} fi fj max((pi-pj)(ti-tj)/100, 0)] / C(M,2),  M = #flagged.
// With t' = 0.01*t and max(x,0) = (x+|x|)/2 over the full ordered square:
//   A = sum_{i,j} fi fj (pi-pj)(t'i-t'j) = 2[M*T - P*Q]   (closed form)
//       T = sum f p t', P = sum f p, Q = sum f t'
//   B = sum_{i,j} fi fj |pi-pj||t'i-t'j|                  (pair loop)
//   Loss = (A + B) / (2 M (M-1))
// Unflagged j staged as (0,0):  B = B_raw - (N - M)*D,  D = sum f |p t'|.
// Inner op: 3 VALU/pair (sub, sub, fma; abs folds into VOP3 modifiers).
// Two-kernel structure measured faster than every fused variant (R4/R5/R7):
// a second tiny dispatch beats any cross-XCD last-block completion protocol.
__global__ __launch_bounds__(256) void pair_kernel(
    const float* __restrict__ pred,
    const float* __restrict__ gt,
    const int* __restrict__ colT,
    const int* __restrict__ colF,
    float* __restrict__ ws)   // [NBLK] B_raw partials, then [NIB*5] scalar sums
{
    __shared__ float2 sj[JTILE];
    const int tid = threadIdx.x;
    const int ib  = blockIdx.x;   // 0..NIB-1
    const int tj  = blockIdx.y;   // 0..NJT-1
    const int ct  = colT[0];      // 0
    const int cf  = colF[0];      // 1

    if (tid < JTILE) {
        const int j = tj * JTILE + tid;
        const float2 g = ((const float2*)gt)[j];
        const float tv = (ct == 0) ? g.x : g.y;
        const float fv = (cf == 0) ? g.x : g.y;
        const float pj = pred[j];
        const bool  fl = (fv == 1.0f);
        sj[tid] = make_float2(fl ? pj : 0.0f, fl ? tv * 0.01f : 0.0f);
    }
    __syncthreads();

    float p[IPT], t[IPT], f[IPT], acc[IPT];
    {
        const int i0 = ib * IBLK + tid * IPT;           // 64B-aligned
        const float4* p4 = (const float4*)(pred + i0);
        const float4* g4 = (const float4*)(gt + 2 * i0);
        float4 pr[IPT / 4], gr[IPT / 2];
        #pragma unroll
        for (int q = 0; q < IPT / 4; ++q) pr[q] = p4[q];
        #pragma unroll
        for (int q = 0; q < IPT / 2; ++q) gr[q] = g4[q];
        #pragma unroll
        for (int k = 0; k < IPT; ++k) {                 // static indices only
            p[k] = ((const float*)pr)[k];
            const float gx = ((const float*)gr)[2 * k];
            const float gy = ((const float*)gr)[2 * k + 1];
            const float tv = (ct == 0) ? gx : gy;
            const float fv = (cf == 0) ? gx : gy;
            t[k] = tv * 0.01f;
            f[k] = (fv == 1.0f) ? 1.0f : 0.0f;
            acc[k] = 0.0f;
        }
    }

    #pragma unroll 4
    for (int jj = 0; jj < JTILE; ++jj) {
        const float2 v = sj[jj];              // ds_read_b64 broadcast (uniform)
        #pragma unroll
        for (int k = 0; k < IPT; ++k)
            acc[k] = fmaf(fabsf(p[k] - v.x), fabsf(t[k] - v.y), acc[k]);
    }

    float s = 0.0f;
    #pragma unroll
    for (int k = 0; k < IPT; ++k) s = fmaf(f[k], acc[k], s);
    for (int off = 32; off > 0; off >>= 1) s += __shfl_down(s, off, 64);
    __shared__ float wsum[4];
    if ((tid & 63) == 0) wsum[tid >> 6] = s;
    __syncthreads();
    if (tid == 0) ws[tj * NIB + ib] = wsum[0] + wsum[1] + wsum[2] + wsum[3];

    // O(N) scalar sums, piggybacked on tj==0 blocks (i-data already live).
    if (tj == 0) {   // block-uniform -> barrier safe
        float c = 0, sp = 0, st = 0, spt = 0, sab = 0;
        #pragma unroll
        for (int k = 0; k < IPT; ++k) {
            const float pt = p[k] * t[k];
            c   += f[k];
            sp   = fmaf(f[k], p[k], sp);
            st   = fmaf(f[k], t[k], st);
            spt  = fmaf(f[k], pt, spt);
            sab  = fmaf(f[k], fabsf(pt), sab);
        }
        for (int off = 32; off > 0; off >>= 1) {
            c   += __shfl_down(c,   off, 64);
            sp  += __shfl_down(sp,  off, 64);
            st  += __shfl_down(st,  off, 64);
            spt += __shfl_down(spt, off, 64);
            sab += __shfl_down(sab, off, 64);
        }
        __shared__ float s5[4][5];
        const int wid = tid >> 6;
        if ((tid & 63) == 0) {
            s5[wid][0] = c;  s5[wid][1] = sp;  s5[wid][2] = st;
            s5[wid][3] = spt; s5[wid][4] = sab;
        }
        __syncthreads();
        if (tid == 0) {
            float* o = ws + SCB + ib * 5;
            #pragma unroll
            for (int m = 0; m < 5; ++m)
                o[m] = s5[0][m] + s5[1][m] + s5[2][m] + s5[3][m];
        }
    }
}

// Single-wave finalize: 512 partials, 8 per lane; no barriers needed.
__global__ __launch_bounds__(64) void finalize(
    const float* __restrict__ ws,
    float* __restrict__ out)
{
    const int tid = threadIdx.x;
    double s = 0.0;
    #pragma unroll
    for (int q = 0; q < NBLK / 64; ++q) s += (double)ws[q * 64 + tid];
    for (int off = 32; off > 0; off >>= 1) s += __shfl_down(s, off, 64);
    if (tid == 0) {
        double M = 0, P = 0, Q = 0, T = 0, D = 0;
        for (int ib = 0; ib < NIB; ++ib) {
            const float* o = ws + SCB + ib * 5;
            M += (double)o[0]; P += (double)o[1]; Q += (double)o[2];
            T += (double)o[3]; D += (double)o[4];
        }
        const double A = 2.0 * (M * T - P * Q);
        const double B = s - ((double)NELEM - M) * D;
        out[0] = (float)((A + B) / (2.0 * M * (M - 1.0)));
    }
}

extern "C" void kernel_launch(void* const* d_in, const int* in_sizes, int n_in,
                              void* d_out, int out_size, void* d_ws, size_t ws_size,
                              hipStream_t stream) {
    const float* pred = (const float*)d_in[0];
    const float* gt   = (const float*)d_in[1];
    const int*   colT = (const int*)d_in[2];
    const int*   colF = (const int*)d_in[3];

    float* ws = (float*)d_ws;   // NBLK + NIB*5 floats

    dim3 grid(NIB, NJT);
    pair_kernel<<<grid, 256, 0, stream>>>(pred, gt, colT, colF, ws);
    finalize<<<1, 64, 0, stream>>>(ws, (float*)d_out);
}